// Round 1
// 251.823 us; speedup vs baseline: 1.0035x; 1.0035x over previous
//
#include <hip/hip_runtime.h>

#define M_DIM 2048
#define K_DIM 4096
#define N_DIM 4096

typedef unsigned short u16;
typedef unsigned int u32;
typedef __bf16 bf16x8 __attribute__((ext_vector_type(8)));
typedef float f32x4 __attribute__((ext_vector_type(4)));
typedef float f4 __attribute__((ext_vector_type(4)));
typedef u16 u16x8 __attribute__((ext_vector_type(8)));
typedef u32 u32x4 __attribute__((ext_vector_type(4)));

// fp32 -> bf16 round-to-nearest-even
__device__ __forceinline__ u16 f2bf(float f) {
    unsigned int u = __float_as_uint(f);
    u += 0x7fffu + ((u >> 16) & 1u);
    return (u16)(u >> 16);
}

// pack two fp32 -> (bf16(lo) | bf16(hi)<<16), RNE
__device__ __forceinline__ u32 pack2(float lo, float hi) {
    u32 a = __float_as_uint(lo); a += 0x7fffu + ((a >> 16) & 1u);
    u32 b = __float_as_uint(hi); b += 0x7fffu + ((b >> 16) & 1u);
    return (a >> 16) | (b & 0xffff0000u);
}

// async global->LDS, 16B per lane. LDS dest must be wave-uniform base + lane*16.
__device__ __forceinline__ void load16(const void* g, void* l) {
    __builtin_amdgcn_global_load_lds(
        (__attribute__((address_space(1))) const void*)g,
        (__attribute__((address_space(3))) void*)l,
        16, 0, 0);
}

// --------------- fused prep v2: LDS-free transpose + x->bf16 ----------------
// blocks [0, 2048): one 64(k) x 128(n) tile of W/mask -> Bt[n][k] bf16.
//   Thread t owns k-octet ko = t&7 (8 consecutive k rows) and 4 n-columns
//   (ng = t>>3). It reads 8x float4 from W and Msk (per wave, each j-load is
//   8 rows x 128B-contiguous segments), masks+packs in REGISTERS (pack2 pairs
//   k and k+1 -> the transpose is intra-thread), then stores one uint4 per n:
//   lanes of an octet-group produce 128B-contiguous Bt segments. No LDS, no
//   __syncthreads, 256B global read per thread (2x the old version).
// blocks [2048, 4096): convert 4096 contiguous floats of x -> xb (16/thread).
__global__ __launch_bounds__(256) void prep(const float* __restrict__ x,
                                            u16* __restrict__ xb,
                                            const float* __restrict__ W,
                                            const float* __restrict__ Msk,
                                            u16* __restrict__ Bt) {
    const int t = threadIdx.x;
    if (blockIdx.x >= 2048) {
        // ---- conv_x: 16 floats/thread ----
        size_t i = ((size_t)(blockIdx.x - 2048) * 256 + t) * 16;
#pragma unroll
        for (int h = 0; h < 2; ++h) {
            f4 v0 = *(const f4*)(x + i + h * 8);
            f4 v1 = *(const f4*)(x + i + h * 8 + 4);
            u16x8 o;
            o[0] = f2bf(v0[0]); o[1] = f2bf(v0[1]); o[2] = f2bf(v0[2]); o[3] = f2bf(v0[3]);
            o[4] = f2bf(v1[0]); o[5] = f2bf(v1[1]); o[6] = f2bf(v1[2]); o[7] = f2bf(v1[3]);
            *(u16x8*)(xb + i + h * 8) = o;
        }
        return;
    }
    const int n0 = (blockIdx.x & 31) * 128;         // 32 n-tiles of 128
    const int k0 = (blockIdx.x >> 5) * 64;          // 64 k-tiles of 64
    const int ko = t & 7;                           // k-octet within tile
    const int ng = t >> 3;                          // n-group (4 cols), 0..31

    const float* Wp = W   + (size_t)(k0 + 8 * ko) * N_DIM + n0 + 4 * ng;
    const float* Mp = Msk + (size_t)(k0 + 8 * ko) * N_DIM + n0 + 4 * ng;

    f4 a[8];
#pragma unroll
    for (int j = 0; j < 8; ++j) {
        f4 wv = *(const f4*)(Wp + (size_t)j * N_DIM);
        f4 mv = *(const f4*)(Mp + (size_t)j * N_DIM);
        a[j][0] = mv[0] != 0.f ? wv[0] : 0.f;
        a[j][1] = mv[1] != 0.f ? wv[1] : 0.f;
        a[j][2] = mv[2] != 0.f ? wv[2] : 0.f;
        a[j][3] = mv[3] != 0.f ? wv[3] : 0.f;
    }

    u16* bp = Bt + (size_t)(n0 + 4 * ng) * K_DIM + k0 + 8 * ko;
#pragma unroll
    for (int i = 0; i < 4; ++i) {                   // n within the float4
        u32x4 o;
        o[0] = pack2(a[0][i], a[1][i]);
        o[1] = pack2(a[2][i], a[3][i]);
        o[2] = pack2(a[4][i], a[5][i]);
        o[3] = pack2(a[6][i], a[7][i]);
        *(u32x4*)(bp + (size_t)i * K_DIM) = o;
    }
}

// ---------------- gemm: C = xb @ Bt^T + bias, XOR-swizzled LDS --------------
// UNCHANGED (869 TF = m97-structure plateau; SQ_LDS_BANK_CONFLICT=0).
__global__ __launch_bounds__(256) void gemm_bt(const u16* __restrict__ A,   // M x K bf16
                                               const u16* __restrict__ Bt,  // N x K bf16
                                               const float* __restrict__ bias,
                                               float* __restrict__ C) {
    __shared__ __align__(16) u16 As[128 * 64];
    __shared__ __align__(16) u16 Bs[128 * 64];

    const int t  = threadIdx.x;
    const int bn = blockIdx.x;
    const int bm = blockIdx.y;

    const int srow   = t >> 3;
    const int schunk = (t & 7) ^ (srow & 7);
    const u16* gA = A  + (size_t)(bm * 128 + srow) * K_DIM + schunk * 8;
    const u16* gB = Bt + (size_t)(bn * 128 + srow) * K_DIM + schunk * 8;
    u16* lA = As + t * 8;
    u16* lB = Bs + t * 8;

    const int lane = t & 63;
    const int wave = t >> 6;
    const int wm = (wave >> 1) * 64;
    const int wn = (wave & 1) * 64;
    const int fr = lane & 15;          // fragment free-dim index
    const int q  = lane >> 4;          // k-quad
    const int sw = fr & 7;             // row-phase for the XOR swizzle
    const int col0 = ((0 + q) ^ sw) * 8;   // kk = 0
    const int col1 = ((4 + q) ^ sw) * 8;   // kk = 32

    f32x4 acc[4][4] = {};

    for (int k0 = 0; k0 < K_DIM; k0 += 64) {
#pragma unroll
        for (int it = 0; it < 4; ++it) {
            load16(gA + k0 + it * 32 * K_DIM, lA + it * 2048);
            load16(gB + k0 + it * 32 * K_DIM, lB + it * 2048);
        }
        __syncthreads();
#pragma unroll
        for (int kx = 0; kx < 2; ++kx) {
            const int col = kx ? col1 : col0;
            bf16x8 af[4], bfr[4];
#pragma unroll
            for (int i = 0; i < 4; ++i)
                af[i] = *(const bf16x8*)(As + (wm + i * 16 + fr) * 64 + col);
#pragma unroll
            for (int j = 0; j < 4; ++j)
                bfr[j] = *(const bf16x8*)(Bs + (wn + j * 16 + fr) * 64 + col);
#pragma unroll
            for (int i = 0; i < 4; ++i)
#pragma unroll
                for (int j = 0; j < 4; ++j)
                    acc[i][j] = __builtin_amdgcn_mfma_f32_16x16x32_bf16(
                        af[i], bfr[j], acc[i][j], 0, 0, 0);
        }
        __syncthreads();
    }

    const int rb = q * 4;
#pragma unroll
    for (int i = 0; i < 4; ++i) {
#pragma unroll
        for (int j = 0; j < 4; ++j) {
            int n = bn * 128 + wn + j * 16 + fr;
            float bv = bias[n];
#pragma unroll
            for (int r = 0; r < 4; ++r) {
                int m = bm * 128 + wm + i * 16 + rb + r;
                C[(size_t)m * N_DIM + n] = acc[i][j][r] + bv;
            }
        }
    }
}

extern "C" void kernel_launch(void* const* d_in, const int* in_sizes, int n_in,
                              void* d_out, int out_size, void* d_ws, size_t ws_size,
                              hipStream_t stream) {
    const float* x    = (const float*)d_in[0];  // 2048 x 4096
    const float* mask = (const float*)d_in[1];  // 4096 x 4096
    const float* W    = (const float*)d_in[2];  // 4096 x 4096
    const float* bias = (const float*)d_in[3];  // 4096
    float* out = (float*)d_out;                 // 2048 x 4096

    u16* Bt = (u16*)d_ws;                                   // N*K bf16 = 32 MB
    u16* xb = (u16*)d_ws + (size_t)N_DIM * K_DIM;           // M*K bf16 = 16 MB

    // prep signature is (x, xb, W, Msk, Bt) — keep argument order exact.
    prep<<<4096, 256, 0, stream>>>(x, xb, W, mask, Bt);
    gemm_bt<<<dim3(N_DIM / 128, M_DIM / 128), 256, 0, stream>>>(xb, Bt, bias, out);
}